// Round 1
// 653.058 us; speedup vs baseline: 1.0204x; 1.0204x over previous
//
#include <hip/hip_runtime.h>
#include <hip/hip_bf16.h>

typedef __attribute__((ext_vector_type(8))) short bf16x8;
typedef __attribute__((ext_vector_type(4))) float f32x4;

__device__ __forceinline__ void async16(const void* g, void* l) {
    __builtin_amdgcn_global_load_lds(
        (const __attribute__((address_space(1))) unsigned int*)g,
        (__attribute__((address_space(3))) unsigned int*)l, 16, 0, 0);
}

// ---------------------------------------------------------------------------
// pack_all: one node = pack_x (10240 blocks) + pack_a (640 blocks).
// pack_x: x5 f32 [16][512][16][300] -> X3 bf16 [16][16][300][512] channel-last.
// pack_a: weights -> A2f bf16 in MFMA-FRAGMENT order:
//   A2f block (g=row/16, kt): 1KB = lane l * 16B, lane l=(sq*16+fl) holds
//   row g*16+fl, k = kt*32 + sq*8 .. +8  (exactly the 16x16x32 A-operand frag)
// ---------------------------------------------------------------------------
__global__ __launch_bounds__(256) void pack_all(const float* __restrict__ x5,
                                                const float* __restrict__ conv_w,
                                                const float* __restrict__ cc_w,
                                                __hip_bfloat16* __restrict__ X3,
                                                __hip_bfloat16* __restrict__ A2f) {
    __shared__ __align__(16) float smem[64 * 65];
    const int f = blockIdx.x;
    if (f < 10240) {
        // ---- pack_x ----
        float(*tile)[65] = (float(*)[65])smem;
        const int ct = f / 1280, r = f % 1280;
        const int wt = r >> 8, bh = r & 255;
        const int b = bh >> 4, h = bh & 15;
        const int w0 = wt * 64, c0 = ct * 64;
        const int lw = (threadIdx.x & 15) * 4;
        const int lc = threadIdx.x >> 4;
#pragma unroll
        for (int i = 0; i < 4; ++i) {
            const int c = lc + i * 16;
            const int w = w0 + lw;
            const float* src = &x5[((size_t)(b * 512 + c0 + c) * 16 + h) * 300 + w];
            float4 v = {0.f, 0.f, 0.f, 0.f};
            if (w + 3 < 300) v = *(const float4*)src;
            else {
                if (w < 300)     v.x = src[0];
                if (w + 1 < 300) v.y = src[1];
                if (w + 2 < 300) v.z = src[2];
            }
            *(float4*)&tile[c][lw] = v;
        }
        __syncthreads();
        const int sc = (threadIdx.x & 15) * 4;
        const int sw0 = threadIdx.x >> 4;
#pragma unroll
        for (int i = 0; i < 4; ++i) {
            const int wl = sw0 + i * 16;
            const int w = w0 + wl;
            if (w < 300) {
                __hip_bfloat16 p[4];
                p[0] = __float2bfloat16(tile[sc + 0][wl]);
                p[1] = __float2bfloat16(tile[sc + 1][wl]);
                p[2] = __float2bfloat16(tile[sc + 2][wl]);
                p[3] = __float2bfloat16(tile[sc + 3][wl]);
                *(uint2*)&X3[(((size_t)(b * 16 + h) * 300 + w)) * 512 + c0 + sc] = *(uint2*)p;
            }
        }
    } else {
        // ---- pack_a ----
        float* w = smem;
        const int co = f - 10240;                 // 0..639
        if (co < 522) {
            const float4* src = (co < 512) ? (const float4*)(conv_w + (size_t)co * 3584)
                                           : (const float4*)(cc_w + (size_t)(co - 512) * 3584);
            for (int i = threadIdx.x; i < 896; i += 256) *(float4*)&w[i * 4] = src[i];
        } else {
            for (int i = threadIdx.x; i < 3584; i += 256) w[i] = 0.f;
        }
        __syncthreads();
        const int g = co >> 4, fl = co & 15;
        for (int chunk = threadIdx.x; chunk < 448; chunk += 256) {
            const int kk0 = chunk * 8;
            const int kt = kk0 >> 5, sq = (kk0 >> 3) & 3;
            __hip_bfloat16 p[8];
#pragma unroll
            for (int j = 0; j < 8; ++j) {
                const int k = kk0 + j;
                p[j] = __float2bfloat16(w[(k & 511) * 7 + (k >> 9)]);
            }
            char* dst = (char*)A2f + (((size_t)g * 112 + kt) * 64 + sq * 16 + fl) * 16;
            *(uint4*)dst = *(uint4*)p;
        }
    }
}

// ---------------------------------------------------------------------------
// conv_gemm: implicit-im2col MFMA GEMM, CONV ROWS ONLY (m 0..511, no padding
// tile any more -- the 10 cc rows moved to scores_gemm).
//  - B (X3) staged via global_load_lds, XOR-swizzled, LDS double-buffered.
//  - A fragments loaded straight from L2-resident A2f (fragment-order,
//    coalesced dwordx4), register double-buffered -> LDS traffic halved.
//  - XCD-aware remap: all X3 reuse inside one XCD's L2.
//  - Launched as TWO half dispatches (m_base = 0 and 2): 768 blocks each =
//    exactly 3 resident blocks/CU (one clean residency round) AND it lowers
//    the per-dispatch duration to ~100 us so any hidden slow kernel shows up
//    in the rocprof top-5 next round.
//  - __launch_bounds__(256,4): 128-reg budget fits ~115 live regs.
//    (256,6) previously forced an ~85-reg budget -> accumulator spill ->
//    7.5 GB scratch writes, MfmaUtil 3%. Do NOT raise the min-waves bound.
// feats written channel-last [b][n][co] bf16.
// ---------------------------------------------------------------------------
__global__ __launch_bounds__(256, 4) void conv_gemm(
    const __hip_bfloat16* __restrict__ A2f, const __hip_bfloat16* __restrict__ X3,
    const float* __restrict__ conv_b,
    __hip_bfloat16* __restrict__ feats, int m_base) {
    __shared__ __align__(16) char lds[16384];   // B only: ph0 [0,8K) ph1 [8K,16K)
    const int tid = threadIdx.x;
    const int wv = tid >> 6;
    const int lane = tid & 63;

    // XCD-aware remap (768 blocks = 8 XCD * 48 (nt,b) * 2 m)
    const int gid = blockIdx.x;
    const int xcd = gid & 7;
    const int j = gid >> 3;                    // 0..95
    const int nb = xcd * 48 + (j >> 1);        // 0..383
    const int m0 = (m_base + (j & 1)) * 128;   // {0,128} or {256,384}
    const int b = nb / 24;
    const int nt = nb % 24;

    // ---- B staging (global -> LDS) ----
    const int row0 = wv * 16 + (lane >> 2);            // 0..63
    const int kseg = (lane & 3) ^ ((lane >> 3) & 3);   // XOR-swizzled source segment
    int n0 = nt * 128 + row0;      if (n0 > 2999) n0 = 2999;
    int n1 = nt * 128 + row0 + 64; if (n1 > 2999) n1 = 2999;
    const char* gB0 = (const char*)X3 + ((size_t)((b * 16 + n0 / 300) * 300 + n0 % 300)) * 1024 + (size_t)kseg * 16;
    const char* gB1 = (const char*)X3 + ((size_t)((b * 16 + n1 / 300) * 300 + n1 % 300)) * 1024 + (size_t)kseg * 16;
    char* lB = lds + wv * 1024 + lane * 16;            // +4096: rows 64..127

    // ---- fragment read offsets ----
    const int wm = (wv & 1) * 64;
    const int wn = (wv >> 1) * 64;
    const int fl = lane & 15;
    const int sq = lane >> 4;
    int boff[4];
#pragma unroll
    for (int i = 0; i < 4; ++i) {
        const int swz = (sq ^ ((fl >> 1) & 3)) * 16;
        boff[i] = (wn + i * 16 + fl) * 64 + swz;
    }
    // A fragment source (fragment-order A2f, coalesced)
    const char* Af = (const char*)A2f;
    const int gb = (m0 >> 4) + ((wv & 1) << 2);        // row-group base for this wave

    f32x4 acc[4][4] = {};
    bf16x8 aC[4], aN[4];

#define ISSUE_B(kt, ph)                                                                \
    {                                                                                  \
        const size_t badd = (size_t)((kt) >> 4) * 307200 + (size_t)((kt) & 15) * 64;   \
        async16(gB0 + badd, lB + (ph) * 8192);                                         \
        async16(gB1 + badd, lB + (ph) * 8192 + 4096);                                  \
    }
#define PRE_A(kt, arr)                                                                 \
    {                                                                                  \
        _Pragma("unroll")                                                              \
        for (int mi = 0; mi < 4; ++mi)                                                 \
            arr[mi] = *(const bf16x8*)(Af + (((size_t)(gb + mi) * 112 + (kt)) << 10) + (lane << 4)); \
    }
#define COMPUTE(ph, arr)                                                               \
    {                                                                                  \
        _Pragma("unroll")                                                              \
        for (int ni = 0; ni < 4; ++ni) {                                               \
            const bf16x8 bv = *(const bf16x8*)(lds + (ph) * 8192 + boff[ni]);          \
            _Pragma("unroll")                                                          \
            for (int mi = 0; mi < 4; ++mi)                                             \
                acc[mi][ni] = __builtin_amdgcn_mfma_f32_16x16x32_bf16(arr[mi], bv, acc[mi][ni], 0, 0, 0); \
        }                                                                              \
    }

    ISSUE_B(0, 0);
    PRE_A(0, aC);
    for (int kt = 0; kt < 112; kt += 2) {
        __syncthreads();                       // vmcnt(0) drain: B(kt) + aC landed
        ISSUE_B(kt + 1, 1);
        PRE_A(kt + 1, aN);
        COMPUTE(0, aC);
        __syncthreads();                       // B(kt+1) + aN landed; buf0 reads done
        if (kt < 110) { ISSUE_B(kt + 2, 0); PRE_A(kt + 2, aC); }
        COMPUTE(1, aN);
    }
#undef ISSUE_B
#undef PRE_A
#undef COMPUTE

    const int quad4 = (lane >> 4) * 4;
#pragma unroll
    for (int ni = 0; ni < 4; ++ni) {
        const int n = nt * 128 + wn + ni * 16 + fl;
        if (n >= 3000) continue;
#pragma unroll
        for (int mi = 0; mi < 4; ++mi) {
            const int cob = m0 + wm + mi * 16 + quad4;   // always < 512 now
            const f32x4 v = acc[mi][ni];
            __hip_bfloat16 p[4];
#pragma unroll
            for (int r = 0; r < 4; ++r)
                p[r] = __float2bfloat16(fmaxf(v[r] + conv_b[cob + r], 0.f));
            *(uint2*)&feats[((size_t)(b * 3000 + n)) * 512 + cob] = *(uint2*)p;
        }
    }
}

// ---------------------------------------------------------------------------
// scores_gemm: the 10 cc rows as a skinny M=16 MFMA GEMM (was 1/5 of
// conv_gemm's matrix-pipe time for 10/128 useful rows). HBM-bound: reads X3
// once (~78 MB). Same proven staging pattern as conv_gemm (XOR-swizzled
// global_load_lds, double-buffered), BK=64 per phase to halve barrier count.
// A fragments: A2f group g=32 (rows 512..521 real, 522..527 zero-padded).
// grid 192 = 8 XCD * (2 b * 12 nt2); block = 256 thr, tile 16 x 256.
// ---------------------------------------------------------------------------
__global__ __launch_bounds__(256) void scores_gemm(
    const __hip_bfloat16* __restrict__ A2f, const __hip_bfloat16* __restrict__ X3,
    const float* __restrict__ cc_b, float* __restrict__ scores) {
    __shared__ __align__(16) char lds[65536];   // 2 phases * 32KB (256 rows * 64B * 2 kt)
    const int tid = threadIdx.x;
    const int wv = tid >> 6;
    const int lane = tid & 63;
    const int gid = blockIdx.x;
    const int xcd = gid & 7;
    const int j = gid >> 3;                    // 0..23
    const int b = xcd * 2 + (j >= 12 ? 1 : 0); // XCD owns b pair (matches conv_gemm)
    const int nt2 = j % 12;                    // 256-wide n tile

    // ---- B staging: 256 rows x 64B per kt; 4 quarters per thread ----
    const int row0 = wv * 16 + (lane >> 2);            // 0..63
    const int kseg = (lane & 3) ^ ((lane >> 3) & 3);
    const char* gB[4];
#pragma unroll
    for (int q = 0; q < 4; ++q) {
        int n = nt2 * 256 + row0 + q * 64;
        if (n > 2999) n = 2999;
        gB[q] = (const char*)X3 + ((size_t)((b * 16 + n / 300) * 300 + n % 300)) * 1024 + (size_t)kseg * 16;
    }
    char* lB = lds + wv * 1024 + lane * 16;

    const int wn = wv * 64;
    const int fl = lane & 15;
    const int sq = lane >> 4;
    int boff[4];
#pragma unroll
    for (int i = 0; i < 4; ++i) {
        const int swz = (sq ^ ((fl >> 1) & 3)) * 16;
        boff[i] = (wn + i * 16 + fl) * 64 + swz;
    }
    // A fragments: group g=32, all kt
    const char* Af = (const char*)A2f + (((size_t)32 * 112) << 10) + (lane << 4);

    f32x4 acc[4] = {};
    bf16x8 aC[2], aN[2];

#define S_ISSUE(ktp, ph)                                                               \
    {                                                                                  \
        const int kt0 = (ktp) * 2;                                                     \
        const size_t ba0 = (size_t)(kt0 >> 4) * 307200 + (size_t)(kt0 & 15) * 64;      \
        const size_t ba1 = (size_t)((kt0 + 1) >> 4) * 307200 + (size_t)((kt0 + 1) & 15) * 64; \
        _Pragma("unroll")                                                              \
        for (int q = 0; q < 4; ++q) {                                                  \
            async16(gB[q] + ba0, lB + (ph) * 32768 + q * 4096);                        \
            async16(gB[q] + ba1, lB + (ph) * 32768 + 16384 + q * 4096);                \
        }                                                                              \
    }
#define S_PREA(ktp, arr)                                                               \
    {                                                                                  \
        arr[0] = *(const bf16x8*)(Af + ((size_t)((ktp) * 2) << 10));                   \
        arr[1] = *(const bf16x8*)(Af + ((size_t)((ktp) * 2 + 1) << 10));               \
    }
#define S_COMP(ph, arr)                                                                \
    {                                                                                  \
        _Pragma("unroll")                                                              \
        for (int kk = 0; kk < 2; ++kk) {                                               \
            _Pragma("unroll")                                                          \
            for (int ni = 0; ni < 4; ++ni) {                                           \
                const bf16x8 bv = *(const bf16x8*)(lds + (ph) * 32768 + kk * 16384 + boff[ni]); \
                acc[ni] = __builtin_amdgcn_mfma_f32_16x16x32_bf16(arr[kk], bv, acc[ni], 0, 0, 0); \
            }                                                                          \
        }                                                                              \
    }

    S_ISSUE(0, 0);
    S_PREA(0, aC);
    for (int ktp = 0; ktp < 56; ktp += 2) {
        __syncthreads();
        S_ISSUE(ktp + 1, 1);
        S_PREA(ktp + 1, aN);
        S_COMP(0, aC);
        __syncthreads();
        if (ktp < 54) { S_ISSUE(ktp + 2, 0); S_PREA(ktp + 2, aC); }
        S_COMP(1, aN);
    }
#undef S_ISSUE
#undef S_PREA
#undef S_COMP

    // D row = cc row k = (lane>>4)*4 + r ; col = n. Rows k>=10 are zero pad.
#pragma unroll
    for (int ni = 0; ni < 4; ++ni) {
        const int n = nt2 * 256 + wn + ni * 16 + fl;
        if (n >= 3000) continue;
#pragma unroll
        for (int r = 0; r < 4; ++r) {
            const int k = sq * 4 + r;
            if (k < 10)
                scores[(size_t)(b * 10 + k) * 3000 + n] = acc[ni][r] + cc_b[k];
        }
    }
}

// ---------------------------------------------------------------------------
// softmax over k=10 (in-place scores->assign), per-block asum partials
// (non-atomic), and zero agg for the agg kernel. grid (16 b, 12 chunks).
// ---------------------------------------------------------------------------
__global__ __launch_bounds__(256) void softmax_assign(float* __restrict__ scores,
                                                      float* __restrict__ asum_part,
                                                      float* __restrict__ agg) {
    const int b = blockIdx.x;
    const int chunk = blockIdx.y;
    const int zbase = (b * 12 + chunk) * 512 + threadIdx.x;
    if (zbase < 81920) agg[zbase] = 0.f;
    if (zbase + 256 < 81920) agg[zbase + 256] = 0.f;

    const int hw = chunk * 256 + threadIdx.x;
    const bool valid = hw < 3000;
    float part[10];
    if (valid) {
        float s[10], mx = -1e30f;
#pragma unroll
        for (int k = 0; k < 10; ++k) { s[k] = scores[(size_t)(b * 10 + k) * 3000 + hw]; mx = fmaxf(mx, s[k]); }
        float sum = 0.f;
#pragma unroll
        for (int k = 0; k < 10; ++k) { part[k] = __expf(s[k] - mx); sum += part[k]; }
        const float inv = 1.f / sum;
#pragma unroll
        for (int k = 0; k < 10; ++k) {
            part[k] *= inv;
            scores[(size_t)(b * 10 + k) * 3000 + hw] = part[k];
        }
    } else {
#pragma unroll
        for (int k = 0; k < 10; ++k) part[k] = 0.f;
    }
    __shared__ float red[4][10];
    const int lane = threadIdx.x & 63, w = threadIdx.x >> 6;
#pragma unroll
    for (int k = 0; k < 10; ++k) {
        float v = part[k];
        for (int off = 32; off; off >>= 1) v += __shfl_xor(v, off, 64);
        if (lane == 0) red[w][k] = v;
    }
    __syncthreads();
    if (threadIdx.x < 10)
        asum_part[(chunk * 16 + b) * 10 + threadIdx.x] =
            red[0][threadIdx.x] + red[1][threadIdx.x] + red[2][threadIdx.x] + red[3][threadIdx.x];
}

// ---------------------------------------------------------------------------
// agg[b][k][c] += sum_hw assign[b][k][hw] * feats[b][hw][c]. grid (40,16):
// 640 blocks (~2.5/CU) instead of 192 (0.75/CU) -- the old grid left most
// CUs idle with a serial 250-iteration latency chain.
// ---------------------------------------------------------------------------
__global__ __launch_bounds__(256) void agg_kernel(const __hip_bfloat16* __restrict__ feats,
                                                  const float* __restrict__ assign,
                                                  float* __restrict__ agg) {
    const int chunk = blockIdx.x, b = blockIdx.y;
    const int c = threadIdx.x * 2;
    float acc0[10], acc1[10];
#pragma unroll
    for (int k = 0; k < 10; ++k) { acc0[k] = 0.f; acc1[k] = 0.f; }
    const int hw0 = chunk * 75;
    for (int i = 0; i < 75; ++i) {
        const int hw = hw0 + i;
        const __hip_bfloat162 f2 = *(const __hip_bfloat162*)&feats[((size_t)(b * 3000 + hw)) * 512 + c];
        const float f0 = __bfloat162float(f2.x), f1 = __bfloat162float(f2.y);
#pragma unroll
        for (int k = 0; k < 10; ++k) {
            const float a = assign[(size_t)(b * 10 + k) * 3000 + hw];
            acc0[k] += a * f0;
            acc1[k] += a * f1;
        }
    }
#pragma unroll
    for (int k = 0; k < 10; ++k) {
        atomicAdd(&agg[(size_t)(b * 10 + k) * 512 + c], acc0[k]);
        atomicAdd(&agg[(size_t)(b * 10 + k) * 512 + c + 1], acc1[k]);
    }
}

// ---------------------------------------------------------------------------
// fc_fused: residual + L2-normalize (k<8) + fc + relu -> out[0:8192].
// grid (16 co-tiles, 16 b), block 256. Residuals live in LDS only.
// ---------------------------------------------------------------------------
__global__ __launch_bounds__(256) void fc_fused(const float* __restrict__ agg,
                                                const float* __restrict__ asum_part,
                                                const float* __restrict__ centroids,
                                                const float* __restrict__ fc_w,
                                                const float* __restrict__ fc_b,
                                                float* __restrict__ out) {
    __shared__ float res[4096];
    __shared__ float sasum[8];
    __shared__ float red[4][8];
    __shared__ float scale[8];
    const int b = blockIdx.y;
    const int t = threadIdx.x;
    if (t < 8) {
        float s = 0.f;
#pragma unroll
        for (int p = 0; p < 12; ++p) s += asum_part[(p * 16 + b) * 10 + t];
        sasum[t] = s;
    }
    __syncthreads();
    float sq[8];
#pragma unroll
    for (int k = 0; k < 8; ++k) sq[k] = 0.f;
#pragma unroll
    for (int jj = 0; jj < 16; ++jj) {
        const int i = t + jj * 256;
        const int k = jj >> 1;
        const int c = i & 511;
        const float r = agg[(size_t)(b * 10 + k) * 512 + c] - sasum[k] * centroids[k * 512 + c];
        res[i] = r;
        sq[k] += r * r;
    }
    const int lane = t & 63, w = t >> 6;
#pragma unroll
    for (int k = 0; k < 8; ++k) {
        float v = sq[k];
        for (int off = 32; off; off >>= 1) v += __shfl_xor(v, off, 64);
        if (lane == 0) red[w][k] = v;
    }
    __syncthreads();
    if (t < 8) {
        const float nrm = sqrtf(red[0][t] + red[1][t] + red[2][t] + red[3][t]);
        scale[t] = 1.f / fmaxf(nrm, 1e-12f);
    }
    __syncthreads();

    const int col = t >> 3;
    const int ks = t & 7;
    const int co = blockIdx.x * 32 + col;
    const float4* w4 = (const float4*)(fc_w + (size_t)co * 4096);
    float acc = 0.f;
    for (int i = ks; i < 1024; i += 8) {
        const float4 wv = w4[i];
        const float4 rv = *(const float4*)&res[i * 4];
        acc += (rv.x * wv.x + rv.y * wv.y + rv.z * wv.z + rv.w * wv.w) * scale[i >> 7];
    }
    acc += __shfl_down(acc, 4, 8);
    acc += __shfl_down(acc, 2, 8);
    acc += __shfl_down(acc, 1, 8);
    if (ks == 0) out[b * 512 + co] = fmaxf(acc + fc_b[co], 0.f);
}

// ---------------------------------------------------------------------------
// logit: XCD-grouped. grid 384.
// ---------------------------------------------------------------------------
__global__ __launch_bounds__(256) void logit_kernel(const float* __restrict__ emb,
                                                    const float* __restrict__ logit_w,
                                                    float* __restrict__ out) {
    __shared__ float se[512];
    const int gid = blockIdx.x;
    const int xcd = gid & 7;
    const int j = gid >> 3;
    const int otile = xcd * 3 + (j >> 4);
    const int b = j & 15;
    se[threadIdx.x] = emb[b * 512 + threadIdx.x];
    se[threadIdx.x + 256] = emb[b * 512 + threadIdx.x + 256];
    __syncthreads();
    const int o = otile * 256 + threadIdx.x;
    if (o < 5994) {
        const float4* w4 = (const float4*)(logit_w + (size_t)o * 512);
        float acc = 0.f;
        for (int i = 0; i < 128; ++i) {
            const float4 w = w4[i];
            acc += w.x * se[4 * i] + w.y * se[4 * i + 1] + w.z * se[4 * i + 2] + w.w * se[4 * i + 3];
        }
        out[8192 + b * 5994 + o] = acc;
    }
}

extern "C" void kernel_launch(void* const* d_in, const int* in_sizes, int n_in,
                              void* d_out, int out_size, void* d_ws, size_t ws_size,
                              hipStream_t stream) {
    (void)in_sizes; (void)n_in; (void)out_size; (void)ws_size;
    const float* x5       = (const float*)d_in[0];
    const float* conv_w   = (const float*)d_in[5];
    const float* conv_b   = (const float*)d_in[6];
    const float* cc_w     = (const float*)d_in[7];
    const float* cc_b     = (const float*)d_in[8];
    const float* centroids= (const float*)d_in[9];
    const float* fc_w     = (const float*)d_in[10];
    const float* fc_b     = (const float*)d_in[11];
    const float* logit_w  = (const float*)d_in[12];
    float* out = (float*)d_out;

    char* ws = (char*)d_ws;
    __hip_bfloat16* X3    = (__hip_bfloat16*)(ws);              // 78,643,200 B
    __hip_bfloat16* A2f   = (__hip_bfloat16*)(ws + 78643200);   //  4,587,520 B (fragment-order)
    __hip_bfloat16* feats = (__hip_bfloat16*)(ws + 83230720);   // 49,152,000 B (channel-last)
    float* scores         = (float*)(ws + 132382720);           //  1,920,000 B
    float* asum_part      = (float*)(ws + 134302720);           //      7,680 B
    float* agg            = (float*)(ws + 134310400);           //    327,680 B

    pack_all<<<dim3(10880), 256, 0, stream>>>(x5, conv_w, cc_w, X3, A2f);
    scores_gemm<<<dim3(192), 256, 0, stream>>>(A2f, X3, cc_b, scores);
    softmax_assign<<<dim3(16, 12), 256, 0, stream>>>(scores, asum_part, agg);
    conv_gemm<<<dim3(768), 256, 0, stream>>>(A2f, X3, conv_b, feats, 0);
    conv_gemm<<<dim3(768), 256, 0, stream>>>(A2f, X3, conv_b, feats, 2);
    agg_kernel<<<dim3(40, 16), 256, 0, stream>>>(feats, scores, agg);
    fc_fused<<<dim3(16, 16), 256, 0, stream>>>(agg, asum_part, centroids, fc_w, fc_b, out);
    logit_kernel<<<dim3(384), 256, 0, stream>>>(out, logit_w, out);
}

// Round 3
// 652.167 us; speedup vs baseline: 1.0218x; 1.0014x over previous
//
#include <hip/hip_runtime.h>
#include <hip/hip_bf16.h>

typedef __attribute__((ext_vector_type(8))) short bf16x8;
typedef __attribute__((ext_vector_type(4))) float f32x4;

__device__ __forceinline__ void async16(const void* g, void* l) {
    __builtin_amdgcn_global_load_lds(
        (const __attribute__((address_space(1))) unsigned int*)g,
        (__attribute__((address_space(3))) unsigned int*)l, 16, 0, 0);
}

// ---------------------------------------------------------------------------
// pack_all: one node = pack_x (10240 blocks) + pack_a (640 blocks).
// pack_x: x5 f32 [16][512][16][300] -> X3 bf16 [16][16][300][512] channel-last.
//   Store phase widened to 16B/lane (uint4) vs the old 8B/lane.
// pack_a: weights -> A2f bf16 in MFMA-FRAGMENT order:
//   A2f block (g=row/16, kt): 1KB = lane l * 16B, lane l=(sq*16+fl) holds
//   row g*16+fl, k = kt*32 + sq*8 .. +8  (exactly the 16x16x32 A-operand frag)
// ---------------------------------------------------------------------------
__global__ __launch_bounds__(256) void pack_all(const float* __restrict__ x5,
                                                const float* __restrict__ conv_w,
                                                const float* __restrict__ cc_w,
                                                __hip_bfloat16* __restrict__ X3,
                                                __hip_bfloat16* __restrict__ A2f) {
    __shared__ __align__(16) float smem[64 * 65];
    const int f = blockIdx.x;
    if (f < 10240) {
        // ---- pack_x ----
        float(*tile)[65] = (float(*)[65])smem;
        const int ct = f / 1280, r = f % 1280;
        const int wt = r >> 8, bh = r & 255;
        const int b = bh >> 4, h = bh & 15;
        const int w0 = wt * 64, c0 = ct * 64;
        const int lw = (threadIdx.x & 15) * 4;
        const int lc = threadIdx.x >> 4;
#pragma unroll
        for (int i = 0; i < 4; ++i) {
            const int c = lc + i * 16;
            const int w = w0 + lw;
            const float* src = &x5[((size_t)(b * 512 + c0 + c) * 16 + h) * 300 + w];
            float4 v = {0.f, 0.f, 0.f, 0.f};
            if (w + 3 < 300) v = *(const float4*)src;
            else {
                if (w < 300)     v.x = src[0];
                if (w + 1 < 300) v.y = src[1];
                if (w + 2 < 300) v.z = src[2];
            }
            *(float4*)&tile[c][lw] = v;
        }
        __syncthreads();
        const int sc = (threadIdx.x & 7) * 8;     // 8 channels -> 16B store
        const int sw0 = threadIdx.x >> 3;         // 0..31
#pragma unroll
        for (int i = 0; i < 2; ++i) {
            const int wl = sw0 + i * 32;
            const int w = w0 + wl;
            if (w < 300) {
                __hip_bfloat16 p[8];
#pragma unroll
                for (int j = 0; j < 8; ++j) p[j] = __float2bfloat16(tile[sc + j][wl]);
                *(uint4*)&X3[(((size_t)(b * 16 + h) * 300 + w)) * 512 + c0 + sc] = *(uint4*)p;
            }
        }
    } else {
        // ---- pack_a ----
        float* w = smem;
        const int co = f - 10240;                 // 0..639
        if (co < 522) {
            const float4* src = (co < 512) ? (const float4*)(conv_w + (size_t)co * 3584)
                                           : (const float4*)(cc_w + (size_t)(co - 512) * 3584);
            for (int i = threadIdx.x; i < 896; i += 256) *(float4*)&w[i * 4] = src[i];
        } else {
            for (int i = threadIdx.x; i < 3584; i += 256) w[i] = 0.f;
        }
        __syncthreads();
        const int g = co >> 4, fl = co & 15;
        for (int chunk = threadIdx.x; chunk < 448; chunk += 256) {
            const int kk0 = chunk * 8;
            const int kt = kk0 >> 5, sq = (kk0 >> 3) & 3;
            __hip_bfloat16 p[8];
#pragma unroll
            for (int j = 0; j < 8; ++j) {
                const int k = kk0 + j;
                p[j] = __float2bfloat16(w[(k & 511) * 7 + (k >> 9)]);
            }
            char* dst = (char*)A2f + (((size_t)g * 112 + kt) * 64 + sq * 16 + fl) * 16;
            *(uint4*)dst = *(uint4*)p;
        }
    }
}

// ---------------------------------------------------------------------------
// scores_gemm: 10 cc rows as a skinny M=16 MFMA GEMM, now with FUSED
// softmax (over k), assign write (in-place buffer), asum partials, and the
// agg zero-fill (agg is accumulated by conv_gemm's atomics afterwards).
// For a given n, the 16 k-values live across the 4 sq-lanes (4 each) ->
// max/sum over k = in-lane fold + shfl_xor(16) + shfl_xor(32).
// grid 192 = 8 XCD * (2 b * 12 nt2); block 256; tile 16 x 256.
// ---------------------------------------------------------------------------
__global__ __launch_bounds__(256) void scores_gemm(
    const __hip_bfloat16* __restrict__ A2f, const __hip_bfloat16* __restrict__ X3,
    const float* __restrict__ cc_b, float* __restrict__ assign,
    float* __restrict__ asum_part, float* __restrict__ agg) {
    __shared__ __align__(16) char lds[65536];   // 2 phases * 32KB (256 rows * 64B * 2 kt)
    __shared__ float sred[4][4][4];             // [wave][sq][r] asum partials
    const int tid = threadIdx.x;
    const int wv = tid >> 6;
    const int lane = tid & 63;
    const int gid = blockIdx.x;
    const int xcd = gid & 7;
    const int j = gid >> 3;                    // 0..23
    const int b = xcd * 2 + (j >= 12 ? 1 : 0);
    const int nt2 = j % 12;                    // 256-wide n tile

    // ---- agg zero (81920 floats over 192 blocks) ----
    {
        const int base = gid * 427;
        for (int i = tid; i < 427; i += 256) {
            const int idx = base + i;
            if (idx < 81920) agg[idx] = 0.f;
        }
    }

    // ---- B staging: 256 rows x 64B per kt; 4 quarters per thread ----
    const int row0 = wv * 16 + (lane >> 2);            // 0..63
    const int kseg = (lane & 3) ^ ((lane >> 3) & 3);
    const char* gB[4];
#pragma unroll
    for (int q = 0; q < 4; ++q) {
        int n = nt2 * 256 + row0 + q * 64;
        if (n > 2999) n = 2999;
        gB[q] = (const char*)X3 + ((size_t)((b * 16 + n / 300) * 300 + n % 300)) * 1024 + (size_t)kseg * 16;
    }
    char* lB = lds + wv * 1024 + lane * 16;

    const int wn = wv * 64;
    const int fl = lane & 15;
    const int sq = lane >> 4;
    int boff[4];
#pragma unroll
    for (int i = 0; i < 4; ++i) {
        const int swz = (sq ^ ((fl >> 1) & 3)) * 16;
        boff[i] = (wn + i * 16 + fl) * 64 + swz;
    }
    // A fragments: group g=32 (rows 512..521 real, 522..527 zero)
    const char* Af = (const char*)A2f + (((size_t)32 * 112) << 10) + (lane << 4);

    f32x4 acc[4] = {};
    bf16x8 aC[2], aN[2];

#define S_ISSUE(ktp, ph)                                                               \
    {                                                                                  \
        const int kt0 = (ktp) * 2;                                                     \
        const size_t ba0 = (size_t)(kt0 >> 4) * 307200 + (size_t)(kt0 & 15) * 64;      \
        const size_t ba1 = (size_t)((kt0 + 1) >> 4) * 307200 + (size_t)((kt0 + 1) & 15) * 64; \
        _Pragma("unroll")                                                              \
        for (int q = 0; q < 4; ++q) {                                                  \
            async16(gB[q] + ba0, lB + (ph) * 32768 + q * 4096);                        \
            async16(gB[q] + ba1, lB + (ph) * 32768 + 16384 + q * 4096);                \
        }                                                                              \
    }
#define S_PREA(ktp, arr)                                                               \
    {                                                                                  \
        arr[0] = *(const bf16x8*)(Af + ((size_t)((ktp) * 2) << 10));                   \
        arr[1] = *(const bf16x8*)(Af + ((size_t)((ktp) * 2 + 1) << 10));               \
    }
#define S_COMP(ph, arr)                                                                \
    {                                                                                  \
        _Pragma("unroll")                                                              \
        for (int kk = 0; kk < 2; ++kk) {                                               \
            _Pragma("unroll")                                                          \
            for (int ni = 0; ni < 4; ++ni) {                                           \
                const bf16x8 bv = *(const bf16x8*)(lds + (ph) * 32768 + kk * 16384 + boff[ni]); \
                acc[ni] = __builtin_amdgcn_mfma_f32_16x16x32_bf16(arr[kk], bv, acc[ni], 0, 0, 0); \
            }                                                                          \
        }                                                                              \
    }

    S_ISSUE(0, 0);
    S_PREA(0, aC);
    for (int ktp = 0; ktp < 56; ktp += 2) {
        __syncthreads();
        S_ISSUE(ktp + 1, 1);
        S_PREA(ktp + 1, aN);
        S_COMP(0, aC);
        __syncthreads();
        if (ktp < 54) { S_ISSUE(ktp + 2, 0); S_PREA(ktp + 2, aC); }
        S_COMP(1, aN);
    }
#undef S_ISSUE
#undef S_PREA
#undef S_COMP

    // ---- fused softmax over k + assign write + asum partials ----
    // lane (sq,fl) holds k = sq*4+r at n = nt2*256 + wn + ni*16 + fl.
    float pa[4] = {0.f, 0.f, 0.f, 0.f};
#pragma unroll
    for (int ni = 0; ni < 4; ++ni) {
        const int n = nt2 * 256 + wn + ni * 16 + fl;
        const bool nval = (n < 3000);
        float s[4];
#pragma unroll
        for (int r = 0; r < 4; ++r) {
            const int k = sq * 4 + r;
            s[r] = (k < 10) ? (acc[ni][r] + cc_b[k]) : -1e30f;
        }
        float mx = fmaxf(fmaxf(s[0], s[1]), fmaxf(s[2], s[3]));
        mx = fmaxf(mx, __shfl_xor(mx, 16, 64));
        mx = fmaxf(mx, __shfl_xor(mx, 32, 64));
        float e[4], es = 0.f;
#pragma unroll
        for (int r = 0; r < 4; ++r) {
            e[r] = (sq * 4 + r < 10) ? __expf(s[r] - mx) : 0.f;
            es += e[r];
        }
        es += __shfl_xor(es, 16, 64);
        es += __shfl_xor(es, 32, 64);
        const float inv = 1.f / es;
#pragma unroll
        for (int r = 0; r < 4; ++r) {
            const int k = sq * 4 + r;
            const float a = e[r] * inv;
            if (nval) {
                if (k < 10) assign[(size_t)(b * 10 + k) * 3000 + n] = a;
                pa[r] += a;
            }
        }
    }
#pragma unroll
    for (int off = 1; off < 16; off <<= 1)
#pragma unroll
        for (int r = 0; r < 4; ++r) pa[r] += __shfl_xor(pa[r], off, 64);
    if (fl == 0) {
#pragma unroll
        for (int r = 0; r < 4; ++r) sred[wv][sq][r] = pa[r];
    }
    __syncthreads();
    if (tid < 10)
        asum_part[(nt2 * 16 + b) * 10 + tid] =
            sred[0][tid >> 2][tid & 3] + sred[1][tid >> 2][tid & 3] +
            sred[2][tid >> 2][tid & 3] + sred[3][tid >> 2][tid & 3];
}

// ---------------------------------------------------------------------------
// conv_gemm: implicit-im2col MFMA GEMM (m 0..511) with FUSED aggregation:
// feats NEVER hits memory. After the K-loop each lane holds a 16co x 4n
// piece of the feats tile; bias+relu in-register, then for each k:
// partial = sum_n assign[k][n]*feats, shfl_xor-reduce over the 16 fl-lanes,
// atomicAdd into agg. Removes 49 MB feats write + 49 MB agg re-read + a
// whole kernel. Requires scores_gemm (assign + agg zero) to run first.
//  - __launch_bounds__(256,4): 128-reg budget. Do NOT raise the min-waves
//    bound (a previous (256,6) forced acc spill -> 7.5 GB scratch).
// grid 1536 = 8 XCD * 48 (b,nt) * 4 m  (4 m-tiles of a pair adjacent).
// ---------------------------------------------------------------------------
__global__ __launch_bounds__(256, 4) void conv_gemm(
    const __hip_bfloat16* __restrict__ A2f, const __hip_bfloat16* __restrict__ X3,
    const float* __restrict__ conv_b, const float* __restrict__ assign,
    float* __restrict__ agg) {
    __shared__ __align__(16) char lds[16384];   // B only: ph0 [0,8K) ph1 [8K,16K)
    const int tid = threadIdx.x;
    const int wv = tid >> 6;
    const int lane = tid & 63;

    // XCD-aware remap
    const int gid = blockIdx.x;
    const int xcd = gid & 7;
    const int j = gid >> 3;                    // 0..191
    const int nb = xcd * 48 + (j >> 2);        // 0..383
    const int m0 = (j & 3) * 128;              // 0,128,256,384
    const int b = nb / 24;
    const int nt = nb % 24;

    // ---- B staging (global -> LDS) ----
    const int row0 = wv * 16 + (lane >> 2);            // 0..63
    const int kseg = (lane & 3) ^ ((lane >> 3) & 3);   // XOR-swizzled source segment
    int n0 = nt * 128 + row0;      if (n0 > 2999) n0 = 2999;
    int n1 = nt * 128 + row0 + 64; if (n1 > 2999) n1 = 2999;
    const char* gB0 = (const char*)X3 + ((size_t)((b * 16 + n0 / 300) * 300 + n0 % 300)) * 1024 + (size_t)kseg * 16;
    const char* gB1 = (const char*)X3 + ((size_t)((b * 16 + n1 / 300) * 300 + n1 % 300)) * 1024 + (size_t)kseg * 16;
    char* lB = lds + wv * 1024 + lane * 16;            // +4096: rows 64..127

    // ---- fragment read offsets ----
    const int wm = (wv & 1) * 64;
    const int wn = (wv >> 1) * 64;
    const int fl = lane & 15;
    const int sq = lane >> 4;
    int boff[4];
#pragma unroll
    for (int i = 0; i < 4; ++i) {
        const int swz = (sq ^ ((fl >> 1) & 3)) * 16;
        boff[i] = (wn + i * 16 + fl) * 64 + swz;
    }
    // A fragment source (fragment-order A2f, coalesced)
    const char* Af = (const char*)A2f;
    const int gb = (m0 >> 4) + ((wv & 1) << 2);        // row-group base for this wave

    f32x4 acc[4][4] = {};
    bf16x8 aC[4], aN[4];

#define ISSUE_B(kt, ph)                                                                \
    {                                                                                  \
        const size_t badd = (size_t)((kt) >> 4) * 307200 + (size_t)((kt) & 15) * 64;   \
        async16(gB0 + badd, lB + (ph) * 8192);                                         \
        async16(gB1 + badd, lB + (ph) * 8192 + 4096);                                  \
    }
#define PRE_A(kt, arr)                                                                 \
    {                                                                                  \
        _Pragma("unroll")                                                              \
        for (int mi = 0; mi < 4; ++mi)                                                 \
            arr[mi] = *(const bf16x8*)(Af + (((size_t)(gb + mi) * 112 + (kt)) << 10) + (lane << 4)); \
    }
#define COMPUTE(ph, arr)                                                               \
    {                                                                                  \
        _Pragma("unroll")                                                              \
        for (int ni = 0; ni < 4; ++ni) {                                               \
            const bf16x8 bv = *(const bf16x8*)(lds + (ph) * 8192 + boff[ni]);          \
            _Pragma("unroll")                                                          \
            for (int mi = 0; mi < 4; ++mi)                                             \
                acc[mi][ni] = __builtin_amdgcn_mfma_f32_16x16x32_bf16(arr[mi], bv, acc[mi][ni], 0, 0, 0); \
        }                                                                              \
    }

    ISSUE_B(0, 0);
    PRE_A(0, aC);
    for (int kt = 0; kt < 112; kt += 2) {
        __syncthreads();                       // vmcnt(0) drain: B(kt) + aC landed
        ISSUE_B(kt + 1, 1);
        PRE_A(kt + 1, aN);
        COMPUTE(0, aC);
        __syncthreads();                       // B(kt+1) + aN landed; buf0 reads done
        if (kt < 110) { ISSUE_B(kt + 2, 0); PRE_A(kt + 2, aC); }
        COMPUTE(1, aN);
    }
#undef ISSUE_B
#undef PRE_A
#undef COMPUTE

    // ---- epilogue: bias+relu in-register, then fused agg ----
    const int quad4 = sq * 4;
#pragma unroll
    for (int mi = 0; mi < 4; ++mi) {
        const int cob = m0 + wm + mi * 16 + quad4;
        const float b0 = conv_b[cob + 0], b1 = conv_b[cob + 1],
                    b2 = conv_b[cob + 2], b3 = conv_b[cob + 3];
#pragma unroll
        for (int ni = 0; ni < 4; ++ni) {
            acc[mi][ni][0] = fmaxf(acc[mi][ni][0] + b0, 0.f);
            acc[mi][ni][1] = fmaxf(acc[mi][ni][1] + b1, 0.f);
            acc[mi][ni][2] = fmaxf(acc[mi][ni][2] + b2, 0.f);
            acc[mi][ni][3] = fmaxf(acc[mi][ni][3] + b3, 0.f);
        }
    }
    int nn[4];
#pragma unroll
    for (int ni = 0; ni < 4; ++ni) nn[ni] = nt * 128 + wn + ni * 16 + fl;
    const float* asg = assign + (size_t)b * 30000;
    for (int k = 0; k < 10; ++k) {
        float av[4];
#pragma unroll
        for (int ni = 0; ni < 4; ++ni)
            av[ni] = (nn[ni] < 3000) ? asg[(size_t)k * 3000 + nn[ni]] : 0.f;
        float part[16];
#pragma unroll
        for (int mi = 0; mi < 4; ++mi)
#pragma unroll
            for (int r = 0; r < 4; ++r)
                part[mi * 4 + r] = av[0] * acc[mi][0][r] + av[1] * acc[mi][1][r]
                                 + av[2] * acc[mi][2][r] + av[3] * acc[mi][3][r];
#pragma unroll
        for (int off = 1; off < 16; off <<= 1)
#pragma unroll
            for (int i = 0; i < 16; ++i)
                part[i] += __shfl_xor(part[i], off, 64);
        if (fl == 0) {
            float* ag = agg + (size_t)(b * 10 + k) * 512;
#pragma unroll
            for (int mi = 0; mi < 4; ++mi)
#pragma unroll
                for (int r = 0; r < 4; ++r)
                    atomicAdd(&ag[m0 + wm + mi * 16 + quad4 + r], part[mi * 4 + r]);
        }
    }
}

// ---------------------------------------------------------------------------
// fc_fused: residual + L2-normalize (k<8) + fc + relu -> out[0:8192].
// grid (16 co-tiles, 16 b), block 256. Residuals live in LDS only.
// ---------------------------------------------------------------------------
__global__ __launch_bounds__(256) void fc_fused(const float* __restrict__ agg,
                                                const float* __restrict__ asum_part,
                                                const float* __restrict__ centroids,
                                                const float* __restrict__ fc_w,
                                                const float* __restrict__ fc_b,
                                                float* __restrict__ out) {
    __shared__ float res[4096];
    __shared__ float sasum[8];
    __shared__ float red[4][8];
    __shared__ float scale[8];
    const int b = blockIdx.y;
    const int t = threadIdx.x;
    if (t < 8) {
        float s = 0.f;
#pragma unroll
        for (int p = 0; p < 12; ++p) s += asum_part[(p * 16 + b) * 10 + t];
        sasum[t] = s;
    }
    __syncthreads();
    float sq[8];
#pragma unroll
    for (int k = 0; k < 8; ++k) sq[k] = 0.f;
#pragma unroll
    for (int jj = 0; jj < 16; ++jj) {
        const int i = t + jj * 256;
        const int k = jj >> 1;
        const int c = i & 511;
        const float r = agg[(size_t)(b * 10 + k) * 512 + c] - sasum[k] * centroids[k * 512 + c];
        res[i] = r;
        sq[k] += r * r;
    }
    const int lane = t & 63, w = t >> 6;
#pragma unroll
    for (int k = 0; k < 8; ++k) {
        float v = sq[k];
        for (int off = 32; off; off >>= 1) v += __shfl_xor(v, off, 64);
        if (lane == 0) red[w][k] = v;
    }
    __syncthreads();
    if (t < 8) {
        const float nrm = sqrtf(red[0][t] + red[1][t] + red[2][t] + red[3][t]);
        scale[t] = 1.f / fmaxf(nrm, 1e-12f);
    }
    __syncthreads();

    const int col = t >> 3;
    const int ks = t & 7;
    const int co = blockIdx.x * 32 + col;
    const float4* w4 = (const float4*)(fc_w + (size_t)co * 4096);
    float acc = 0.f;
    for (int i = ks; i < 1024; i += 8) {
        const float4 wv = w4[i];
        const float4 rv = *(const float4*)&res[i * 4];
        acc += (rv.x * wv.x + rv.y * wv.y + rv.z * wv.z + rv.w * wv.w) * scale[i >> 7];
    }
    acc += __shfl_down(acc, 4, 8);
    acc += __shfl_down(acc, 2, 8);
    acc += __shfl_down(acc, 1, 8);
    if (ks == 0) out[b * 512 + co] = fmaxf(acc + fc_b[co], 0.f);
}

// ---------------------------------------------------------------------------
// logit: XCD-grouped. grid 384.
// ---------------------------------------------------------------------------
__global__ __launch_bounds__(256) void logit_kernel(const float* __restrict__ emb,
                                                    const float* __restrict__ logit_w,
                                                    float* __restrict__ out) {
    __shared__ float se[512];
    const int gid = blockIdx.x;
    const int xcd = gid & 7;
    const int j = gid >> 3;
    const int otile = xcd * 3 + (j >> 4);
    const int b = j & 15;
    se[threadIdx.x] = emb[b * 512 + threadIdx.x];
    se[threadIdx.x + 256] = emb[b * 512 + threadIdx.x + 256];
    __syncthreads();
    const int o = otile * 256 + threadIdx.x;
    if (o < 5994) {
        const float4* w4 = (const float4*)(logit_w + (size_t)o * 512);
        float acc = 0.f;
        for (int i = 0; i < 128; ++i) {
            const float4 w = w4[i];
            acc += w.x * se[4 * i] + w.y * se[4 * i + 1] + w.z * se[4 * i + 2] + w.w * se[4 * i + 3];
        }
        out[8192 + b * 5994 + o] = acc;
    }
}

extern "C" void kernel_launch(void* const* d_in, const int* in_sizes, int n_in,
                              void* d_out, int out_size, void* d_ws, size_t ws_size,
                              hipStream_t stream) {
    (void)in_sizes; (void)n_in; (void)out_size; (void)ws_size;
    const float* x5       = (const float*)d_in[0];
    const float* conv_w   = (const float*)d_in[5];
    const float* conv_b   = (const float*)d_in[6];
    const float* cc_w     = (const float*)d_in[7];
    const float* cc_b     = (const float*)d_in[8];
    const float* centroids= (const float*)d_in[9];
    const float* fc_w     = (const float*)d_in[10];
    const float* fc_b     = (const float*)d_in[11];
    const float* logit_w  = (const float*)d_in[12];
    float* out = (float*)d_out;

    char* ws = (char*)d_ws;
    __hip_bfloat16* X3  = (__hip_bfloat16*)(ws);              // 78,643,200 B
    __hip_bfloat16* A2f = (__hip_bfloat16*)(ws + 78643200);   //  4,587,520 B (fragment-order)
    float* assign       = (float*)(ws + 83230720);            //  1,920,000 B
    float* asum_part    = (float*)(ws + 85150720);            //      7,680 B
    float* agg          = (float*)(ws + 85158400);            //    327,680 B

    pack_all<<<dim3(10880), 256, 0, stream>>>(x5, conv_w, cc_w, X3, A2f);
    scores_gemm<<<dim3(192), 256, 0, stream>>>(A2f, X3, cc_b, assign, asum_part, agg);
    conv_gemm<<<dim3(1536), 256, 0, stream>>>(A2f, X3, conv_b, assign, agg);
    fc_fused<<<dim3(16, 16), 256, 0, stream>>>(agg, asum_part, centroids, fc_w, fc_b, out);
    logit_kernel<<<dim3(384), 256, 0, stream>>>(out, logit_w, out);
}

// Round 4
// 603.314 us; speedup vs baseline: 1.1045x; 1.0810x over previous
//
#include <hip/hip_runtime.h>
#include <hip/hip_bf16.h>

typedef __attribute__((ext_vector_type(8))) short bf16x8;
typedef __attribute__((ext_vector_type(4))) float f32x4;

__device__ __forceinline__ void async16(const void* g, void* l) {
    __builtin_amdgcn_global_load_lds(
        (const __attribute__((address_space(1))) unsigned int*)g,
        (__attribute__((address_space(3))) unsigned int*)l, 16, 0, 0);
}

// ---------------------------------------------------------------------------
// pack_all: one node = pack_x (10240 blocks) + pack_a (640 blocks).
// pack_x: x5 f32 [16][512][16][300] -> X3 bf16 [16][16][300][512] channel-last.
// pack_a: weights -> A2f bf16 in MFMA-FRAGMENT order:
//   A2f block (g=row/16, kt): 1KB = lane l * 16B, lane l=(sq*16+fl) holds
//   row g*16+fl, k = kt*32 + sq*8 .. +8  (exactly the 16x16x32 A-operand frag)
// ---------------------------------------------------------------------------
__global__ __launch_bounds__(256) void pack_all(const float* __restrict__ x5,
                                                const float* __restrict__ conv_w,
                                                const float* __restrict__ cc_w,
                                                __hip_bfloat16* __restrict__ X3,
                                                __hip_bfloat16* __restrict__ A2f) {
    __shared__ __align__(16) float smem[64 * 65];
    const int f = blockIdx.x;
    if (f < 10240) {
        // ---- pack_x ----
        float(*tile)[65] = (float(*)[65])smem;
        const int ct = f / 1280, r = f % 1280;
        const int wt = r >> 8, bh = r & 255;
        const int b = bh >> 4, h = bh & 15;
        const int w0 = wt * 64, c0 = ct * 64;
        const int lw = (threadIdx.x & 15) * 4;
        const int lc = threadIdx.x >> 4;
#pragma unroll
        for (int i = 0; i < 4; ++i) {
            const int c = lc + i * 16;
            const int w = w0 + lw;
            const float* src = &x5[((size_t)(b * 512 + c0 + c) * 16 + h) * 300 + w];
            float4 v = {0.f, 0.f, 0.f, 0.f};
            if (w + 3 < 300) v = *(const float4*)src;
            else {
                if (w < 300)     v.x = src[0];
                if (w + 1 < 300) v.y = src[1];
                if (w + 2 < 300) v.z = src[2];
            }
            *(float4*)&tile[c][lw] = v;
        }
        __syncthreads();
        const int sc = (threadIdx.x & 7) * 8;     // 8 channels -> 16B store
        const int sw0 = threadIdx.x >> 3;         // 0..31
#pragma unroll
        for (int i = 0; i < 2; ++i) {
            const int wl = sw0 + i * 32;
            const int w = w0 + wl;
            if (w < 300) {
                __hip_bfloat16 p[8];
#pragma unroll
                for (int j = 0; j < 8; ++j) p[j] = __float2bfloat16(tile[sc + j][wl]);
                *(uint4*)&X3[(((size_t)(b * 16 + h) * 300 + w)) * 512 + c0 + sc] = *(uint4*)p;
            }
        }
    } else {
        // ---- pack_a ----
        float* w = smem;
        const int co = f - 10240;                 // 0..639
        if (co < 522) {
            const float4* src = (co < 512) ? (const float4*)(conv_w + (size_t)co * 3584)
                                           : (const float4*)(cc_w + (size_t)(co - 512) * 3584);
            for (int i = threadIdx.x; i < 896; i += 256) *(float4*)&w[i * 4] = src[i];
        } else {
            for (int i = threadIdx.x; i < 3584; i += 256) w[i] = 0.f;
        }
        __syncthreads();
        const int g = co >> 4, fl = co & 15;
        for (int chunk = threadIdx.x; chunk < 448; chunk += 256) {
            const int kk0 = chunk * 8;
            const int kt = kk0 >> 5, sq = (kk0 >> 3) & 3;
            __hip_bfloat16 p[8];
#pragma unroll
            for (int j = 0; j < 8; ++j) {
                const int k = kk0 + j;
                p[j] = __float2bfloat16(w[(k & 511) * 7 + (k >> 9)]);
            }
            char* dst = (char*)A2f + (((size_t)g * 112 + kt) * 64 + sq * 16 + fl) * 16;
            *(uint4*)dst = *(uint4*)p;
        }
    }
}

// ---------------------------------------------------------------------------
// scores_gemm: 10 cc rows, M=16 MFMA, BARRIER-FREE + LDS-FREE.
// Old version: 192 blocks = 0.75/CU -> every barrier/load latency exposed.
// M=16 has zero B-reuse, so staging bought nothing: each lane now loads its
// A- and B-fragments straight from global (dwordx4; a wave touches exactly
// 16 distinct 64B lines per load). X3 is L3-resident so the 7-tap re-read
// is absorbed. Fused softmax/assign/asum epilogue kept; also zeroes agg.
// grid 768 = 8 XCD * (2 b * 48 nt of 64 n); block 256 (4 waves * 16 n).
// ---------------------------------------------------------------------------
__global__ __launch_bounds__(256) void scores_gemm(
    const __hip_bfloat16* __restrict__ A2f, const __hip_bfloat16* __restrict__ X3,
    const float* __restrict__ cc_b, float* __restrict__ assign,
    float* __restrict__ asum_part, float* __restrict__ agg) {
    __shared__ float sred[4][4][4];            // [wave][sq][r] asum partials
    const int tid = threadIdx.x;
    const int wv = tid >> 6;
    const int lane = tid & 63;
    const int fl = lane & 15;
    const int sq = lane >> 4;
    const int gid = blockIdx.x;
    const int xcd = gid & 7;
    const int j = gid >> 3;                    // 0..95
    const int b = xcd * 2 + (j >= 48 ? 1 : 0);
    const int nt = j % 48;                     // 64-wide n tile

    // ---- agg zero (81920 floats over 768 blocks) ----
    {
        const int base = gid * 107;
        for (int i = tid; i < 107; i += 256) {
            const int idx = base + i;
            if (idx < 81920) agg[idx] = 0.f;
        }
    }

    // this lane's output column n; B-frag source row (clamped for pad lanes)
    const int n = nt * 64 + wv * 16 + fl;
    const int nc = n > 2999 ? 2999 : n;
    const char* gB = (const char*)X3 + ((size_t)(b * 4800 + nc)) * 1024 + sq * 16;
    const char* Af = (const char*)A2f + (((size_t)32 * 112) << 10) + ((size_t)lane << 4);

    f32x4 acc = {};
#pragma unroll 4
    for (int kt = 0; kt < 112; ++kt) {
        const bf16x8 a  = *(const bf16x8*)(Af + ((size_t)kt << 10));
        const bf16x8 bv = *(const bf16x8*)(gB + (size_t)(kt >> 4) * 307200 + (size_t)(kt & 15) * 64);
        acc = __builtin_amdgcn_mfma_f32_16x16x32_bf16(a, bv, acc, 0, 0, 0);
    }

    // ---- fused softmax over k + assign write + asum partials ----
    float s[4];
#pragma unroll
    for (int r = 0; r < 4; ++r) {
        const int k = sq * 4 + r;
        s[r] = (k < 10) ? (acc[r] + cc_b[k]) : -1e30f;
    }
    float mx = fmaxf(fmaxf(s[0], s[1]), fmaxf(s[2], s[3]));
    mx = fmaxf(mx, __shfl_xor(mx, 16, 64));
    mx = fmaxf(mx, __shfl_xor(mx, 32, 64));
    float e[4], es = 0.f;
#pragma unroll
    for (int r = 0; r < 4; ++r) {
        e[r] = (sq * 4 + r < 10) ? __expf(s[r] - mx) : 0.f;
        es += e[r];
    }
    es += __shfl_xor(es, 16, 64);
    es += __shfl_xor(es, 32, 64);
    const float inv = 1.f / es;
    const bool nval = (n < 3000);
    float pa[4];
#pragma unroll
    for (int r = 0; r < 4; ++r) {
        const int k = sq * 4 + r;
        const float a = e[r] * inv;
        pa[r] = nval ? a : 0.f;
        if (nval && k < 10) assign[(size_t)(b * 10 + k) * 3000 + n] = a;
    }
#pragma unroll
    for (int off = 1; off < 16; off <<= 1)
#pragma unroll
        for (int r = 0; r < 4; ++r) pa[r] += __shfl_xor(pa[r], off, 64);
    if (fl == 0) {
#pragma unroll
        for (int r = 0; r < 4; ++r) sred[wv][sq][r] = pa[r];
    }
    __syncthreads();
    if (tid < 10)
        asum_part[(nt * 16 + b) * 10 + tid] =
            sred[0][tid >> 2][tid & 3] + sred[1][tid >> 2][tid & 3] +
            sred[2][tid >> 2][tid & 3] + sred[3][tid >> 2][tid & 3];
}

// ---------------------------------------------------------------------------
// conv_gemm: implicit-im2col MFMA GEMM (m 0..511) with FUSED aggregation.
// Epilogue v2: transpose-reduce (15 shfl/k vs 64 -- same pairing tree, so
// bit-identical sums; after 4 steps lane fl owns slot bitrev4(fl)), all 64
// lanes do their own atomics, and wave pairs sharing a co-half (0<->2, 1<->3)
// combine through the dead LDS staging buffer first -> global atomics halved
// (2560 -> 1280/block, ~31 MB HBM atomic traffic).
//  - __launch_bounds__(256,4): 128-reg budget. Do NOT raise the min-waves
//    bound (a previous (256,6) forced acc spill -> 7.5 GB scratch).
// grid 1536 = 8 XCD * 48 (b,nt) * 4 m.
// ---------------------------------------------------------------------------
__global__ __launch_bounds__(256, 4) void conv_gemm(
    const __hip_bfloat16* __restrict__ A2f, const __hip_bfloat16* __restrict__ X3,
    const float* __restrict__ conv_b, const float* __restrict__ assign,
    float* __restrict__ agg) {
    __shared__ __align__(16) char lds[16384];   // B only: ph0 [0,8K) ph1 [8K,16K)
    const int tid = threadIdx.x;
    const int wv = tid >> 6;
    const int lane = tid & 63;

    // XCD-aware remap
    const int gid = blockIdx.x;
    const int xcd = gid & 7;
    const int j = gid >> 3;                    // 0..191
    const int nb = xcd * 48 + (j >> 2);        // 0..383
    const int m0 = (j & 3) * 128;              // 0,128,256,384
    const int b = nb / 24;
    const int nt = nb % 24;

    // ---- B staging (global -> LDS) ----
    const int row0 = wv * 16 + (lane >> 2);            // 0..63
    const int kseg = (lane & 3) ^ ((lane >> 3) & 3);   // XOR-swizzled source segment
    int n0 = nt * 128 + row0;      if (n0 > 2999) n0 = 2999;
    int n1 = nt * 128 + row0 + 64; if (n1 > 2999) n1 = 2999;
    const char* gB0 = (const char*)X3 + ((size_t)((b * 16 + n0 / 300) * 300 + n0 % 300)) * 1024 + (size_t)kseg * 16;
    const char* gB1 = (const char*)X3 + ((size_t)((b * 16 + n1 / 300) * 300 + n1 % 300)) * 1024 + (size_t)kseg * 16;
    char* lB = lds + wv * 1024 + lane * 16;            // +4096: rows 64..127

    // ---- fragment read offsets ----
    const int wm = (wv & 1) * 64;
    const int wn = (wv >> 1) * 64;
    const int fl = lane & 15;
    const int sq = lane >> 4;
    int boff[4];
#pragma unroll
    for (int i = 0; i < 4; ++i) {
        const int swz = (sq ^ ((fl >> 1) & 3)) * 16;
        boff[i] = (wn + i * 16 + fl) * 64 + swz;
    }
    // A fragment source (fragment-order A2f, coalesced)
    const char* Af = (const char*)A2f;
    const int gb = (m0 >> 4) + ((wv & 1) << 2);        // row-group base for this wave

    f32x4 acc[4][4] = {};
    bf16x8 aC[4], aN[4];

#define ISSUE_B(kt, ph)                                                                \
    {                                                                                  \
        const size_t badd = (size_t)((kt) >> 4) * 307200 + (size_t)((kt) & 15) * 64;   \
        async16(gB0 + badd, lB + (ph) * 8192);                                         \
        async16(gB1 + badd, lB + (ph) * 8192 + 4096);                                  \
    }
#define PRE_A(kt, arr)                                                                 \
    {                                                                                  \
        _Pragma("unroll")                                                              \
        for (int mi = 0; mi < 4; ++mi)                                                 \
            arr[mi] = *(const bf16x8*)(Af + (((size_t)(gb + mi) * 112 + (kt)) << 10) + (lane << 4)); \
    }
#define COMPUTE(ph, arr)                                                               \
    {                                                                                  \
        _Pragma("unroll")                                                              \
        for (int ni = 0; ni < 4; ++ni) {                                               \
            const bf16x8 bv = *(const bf16x8*)(lds + (ph) * 8192 + boff[ni]);          \
            _Pragma("unroll")                                                          \
            for (int mi = 0; mi < 4; ++mi)                                             \
                acc[mi][ni] = __builtin_amdgcn_mfma_f32_16x16x32_bf16(arr[mi], bv, acc[mi][ni], 0, 0, 0); \
        }                                                                              \
    }

    ISSUE_B(0, 0);
    PRE_A(0, aC);
    for (int kt = 0; kt < 112; kt += 2) {
        __syncthreads();                       // vmcnt(0) drain: B(kt) + aC landed
        ISSUE_B(kt + 1, 1);
        PRE_A(kt + 1, aN);
        COMPUTE(0, aC);
        __syncthreads();                       // B(kt+1) + aN landed; buf0 reads done
        if (kt < 110) { ISSUE_B(kt + 2, 0); PRE_A(kt + 2, aC); }
        COMPUTE(1, aN);
    }
#undef ISSUE_B
#undef PRE_A
#undef COMPUTE

    // ---- epilogue: bias+relu in-register, then fused agg ----
    const int quad4 = sq * 4;
#pragma unroll
    for (int mi = 0; mi < 4; ++mi) {
        const int cob = m0 + wm + mi * 16 + quad4;
        const float b0 = conv_b[cob + 0], b1 = conv_b[cob + 1],
                    b2 = conv_b[cob + 2], b3 = conv_b[cob + 3];
#pragma unroll
        for (int ni = 0; ni < 4; ++ni) {
            acc[mi][ni][0] = fmaxf(acc[mi][ni][0] + b0, 0.f);
            acc[mi][ni][1] = fmaxf(acc[mi][ni][1] + b1, 0.f);
            acc[mi][ni][2] = fmaxf(acc[mi][ni][2] + b2, 0.f);
            acc[mi][ni][3] = fmaxf(acc[mi][ni][3] + b3, 0.f);
        }
    }
    int nn[4];
#pragma unroll
    for (int ni = 0; ni < 4; ++ni) nn[ni] = nt * 128 + wn + ni * 16 + fl;
    const float* asg = assign + (size_t)b * 30000;
    // lane will own slot s = bitrev4(fl) after the transpose-reduce
    const int s_ = ((fl & 1) << 3) | ((fl & 2) << 1) | ((fl & 4) >> 1) | ((fl & 8) >> 3);
    const int co_off = (s_ >> 2) * 16 + quad4 + (s_ & 3);    // 0..63 within wm half
    float red10[10];
    for (int k = 0; k < 10; ++k) {
        float av[4];
#pragma unroll
        for (int ni = 0; ni < 4; ++ni)
            av[ni] = (nn[ni] < 3000) ? asg[(size_t)k * 3000 + nn[ni]] : 0.f;
        float part[16];
#pragma unroll
        for (int mi = 0; mi < 4; ++mi)
#pragma unroll
            for (int r = 0; r < 4; ++r)
                part[mi * 4 + r] = av[0] * acc[mi][0][r] + av[1] * acc[mi][1][r]
                                 + av[2] * acc[mi][2][r] + av[3] * acc[mi][3][r];
        // butterfly transpose-reduce over the 16 fl lanes: 8+4+2+1 = 15 shfl
#pragma unroll
        for (int bit = 0; bit < 4; ++bit) {
            const int off = 1 << bit;
            const int h = 8 >> bit;
            const bool hi = (fl >> bit) & 1;
#pragma unroll
            for (int jj = 0; jj < h; ++jj) {
                const float mine = hi ? part[jj + h] : part[jj];
                const float send = hi ? part[jj] : part[jj + h];
                part[jj] = mine + __shfl_xor(send, off, 64);
            }
        }
        red10[k] = part[0];
    }
    // cross-wave combine: waves 0,1 (wn=0) park in dead ph0 LDS; waves 2,3 add
    float* sagg = (float*)lds;                 // [2 wm-half][10 k][64 co_off]
    if (wv < 2) {
#pragma unroll
        for (int k = 0; k < 10; ++k) sagg[((wv * 10 + k) << 6) + co_off] = red10[k];
    }
    __syncthreads();
    if (wv >= 2) {
        const int wmh = wv & 1;
#pragma unroll
        for (int k = 0; k < 10; ++k) {
            const float v = red10[k] + sagg[((wmh * 10 + k) << 6) + co_off];
            atomicAdd(&agg[(size_t)(b * 10 + k) * 512 + m0 + wm + co_off], v);
        }
    }
}

// ---------------------------------------------------------------------------
// fc_fused: residual + L2-normalize (k<8) + fc + relu -> out[0:8192].
// grid (16 co-tiles, 16 b), block 256. Residuals live in LDS only.
// ---------------------------------------------------------------------------
__global__ __launch_bounds__(256) void fc_fused(const float* __restrict__ agg,
                                                const float* __restrict__ asum_part,
                                                const float* __restrict__ centroids,
                                                const float* __restrict__ fc_w,
                                                const float* __restrict__ fc_b,
                                                float* __restrict__ out) {
    __shared__ float res[4096];
    __shared__ float sasum[8];
    __shared__ float red[4][8];
    __shared__ float scale[8];
    const int b = blockIdx.y;
    const int t = threadIdx.x;
    if (t < 8) {
        float s = 0.f;
#pragma unroll
        for (int p = 0; p < 48; ++p) s += asum_part[(p * 16 + b) * 10 + t];
        sasum[t] = s;
    }
    __syncthreads();
    float sq[8];
#pragma unroll
    for (int k = 0; k < 8; ++k) sq[k] = 0.f;
#pragma unroll
    for (int jj = 0; jj < 16; ++jj) {
        const int i = t + jj * 256;
        const int k = jj >> 1;
        const int c = i & 511;
        const float r = agg[(size_t)(b * 10 + k) * 512 + c] - sasum[k] * centroids[k * 512 + c];
        res[i] = r;
        sq[k] += r * r;
    }
    const int lane = t & 63, w = t >> 6;
#pragma unroll
    for (int k = 0; k < 8; ++k) {
        float v = sq[k];
        for (int off = 32; off; off >>= 1) v += __shfl_xor(v, off, 64);
        if (lane == 0) red[w][k] = v;
    }
    __syncthreads();
    if (t < 8) {
        const float nrm = sqrtf(red[0][t] + red[1][t] + red[2][t] + red[3][t]);
        scale[t] = 1.f / fmaxf(nrm, 1e-12f);
    }
    __syncthreads();

    const int col = t >> 3;
    const int ks = t & 7;
    const int co = blockIdx.x * 32 + col;
    const float4* w4 = (const float4*)(fc_w + (size_t)co * 4096);
    float acc = 0.f;
    for (int i = ks; i < 1024; i += 8) {
        const float4 wv = w4[i];
        const float4 rv = *(const float4*)&res[i * 4];
        acc += (rv.x * wv.x + rv.y * wv.y + rv.z * wv.z + rv.w * wv.w) * scale[i >> 7];
    }
    acc += __shfl_down(acc, 4, 8);
    acc += __shfl_down(acc, 2, 8);
    acc += __shfl_down(acc, 1, 8);
    if (ks == 0) out[b * 512 + co] = fmaxf(acc + fc_b[co], 0.f);
}

// ---------------------------------------------------------------------------
// logit: XCD-grouped. grid 384.
// ---------------------------------------------------------------------------
__global__ __launch_bounds__(256) void logit_kernel(const float* __restrict__ emb,
                                                    const float* __restrict__ logit_w,
                                                    float* __restrict__ out) {
    __shared__ float se[512];
    const int gid = blockIdx.x;
    const int xcd = gid & 7;
    const int j = gid >> 3;
    const int otile = xcd * 3 + (j >> 4);
    const int b = j & 15;
    se[threadIdx.x] = emb[b * 512 + threadIdx.x];
    se[threadIdx.x + 256] = emb[b * 512 + threadIdx.x + 256];
    __syncthreads();
    const int o = otile * 256 + threadIdx.x;
    if (o < 5994) {
        const float4* w4 = (const float4*)(logit_w + (size_t)o * 512);
        float acc = 0.f;
        for (int i = 0; i < 128; ++i) {
            const float4 w = w4[i];
            acc += w.x * se[4 * i] + w.y * se[4 * i + 1] + w.z * se[4 * i + 2] + w.w * se[4 * i + 3];
        }
        out[8192 + b * 5994 + o] = acc;
    }
}

extern "C" void kernel_launch(void* const* d_in, const int* in_sizes, int n_in,
                              void* d_out, int out_size, void* d_ws, size_t ws_size,
                              hipStream_t stream) {
    (void)in_sizes; (void)n_in; (void)out_size; (void)ws_size;
    const float* x5       = (const float*)d_in[0];
    const float* conv_w   = (const float*)d_in[5];
    const float* conv_b   = (const float*)d_in[6];
    const float* cc_w     = (const float*)d_in[7];
    const float* cc_b     = (const float*)d_in[8];
    const float* centroids= (const float*)d_in[9];
    const float* fc_w     = (const float*)d_in[10];
    const float* fc_b     = (const float*)d_in[11];
    const float* logit_w  = (const float*)d_in[12];
    float* out = (float*)d_out;

    char* ws = (char*)d_ws;
    __hip_bfloat16* X3  = (__hip_bfloat16*)(ws);              // 78,643,200 B
    __hip_bfloat16* A2f = (__hip_bfloat16*)(ws + 78643200);   //  4,587,520 B (fragment-order)
    float* assign       = (float*)(ws + 83230720);            //  1,920,000 B
    float* asum_part    = (float*)(ws + 85150720);            //     30,720 B (48 partials)
    float* agg          = (float*)(ws + 85181440);            //    327,680 B

    pack_all<<<dim3(10880), 256, 0, stream>>>(x5, conv_w, cc_w, X3, A2f);
    scores_gemm<<<dim3(768), 256, 0, stream>>>(A2f, X3, cc_b, assign, asum_part, agg);
    conv_gemm<<<dim3(1536), 256, 0, stream>>>(A2f, X3, conv_b, assign, agg);
    fc_fused<<<dim3(16, 16), 256, 0, stream>>>(agg, asum_part, centroids, fc_w, fc_b, out);
    logit_kernel<<<dim3(384), 256, 0, stream>>>(out, logit_w, out);
}

// Round 5
// 537.344 us; speedup vs baseline: 1.2401x; 1.1228x over previous
//
#include <hip/hip_runtime.h>
#include <hip/hip_bf16.h>

typedef __attribute__((ext_vector_type(8))) short bf16x8;
typedef __attribute__((ext_vector_type(4))) float f32x4;

__device__ __forceinline__ void async16(const void* g, void* l) {
    __builtin_amdgcn_global_load_lds(
        (const __attribute__((address_space(1))) unsigned int*)g,
        (__attribute__((address_space(3))) unsigned int*)l, 16, 0, 0);
}

// ---------------------------------------------------------------------------
// pack_all: one node = pack_x (10240 blocks) + pack_a (640 blocks).
// pack_x: x5 f32 [16][512][16][300] -> X3 bf16 [16][16][300][512] channel-last.
// pack_a: weights -> A2f bf16 in MFMA-FRAGMENT order:
//   A2f block (g=row/16, kt): 1KB = lane l * 16B, lane l=(sq*16+fl) holds
//   row g*16+fl, k = kt*32 + sq*8 .. +8  (exactly the 16x16x32 A-operand frag)
// ---------------------------------------------------------------------------
__global__ __launch_bounds__(256) void pack_all(const float* __restrict__ x5,
                                                const float* __restrict__ conv_w,
                                                const float* __restrict__ cc_w,
                                                __hip_bfloat16* __restrict__ X3,
                                                __hip_bfloat16* __restrict__ A2f) {
    __shared__ __align__(16) float smem[64 * 65];
    const int f = blockIdx.x;
    if (f < 10240) {
        // ---- pack_x ----
        float(*tile)[65] = (float(*)[65])smem;
        const int ct = f / 1280, r = f % 1280;
        const int wt = r >> 8, bh = r & 255;
        const int b = bh >> 4, h = bh & 15;
        const int w0 = wt * 64, c0 = ct * 64;
        const int lw = (threadIdx.x & 15) * 4;
        const int lc = threadIdx.x >> 4;
#pragma unroll
        for (int i = 0; i < 4; ++i) {
            const int c = lc + i * 16;
            const int w = w0 + lw;
            const float* src = &x5[((size_t)(b * 512 + c0 + c) * 16 + h) * 300 + w];
            float4 v = {0.f, 0.f, 0.f, 0.f};
            if (w + 3 < 300) v = *(const float4*)src;
            else {
                if (w < 300)     v.x = src[0];
                if (w + 1 < 300) v.y = src[1];
                if (w + 2 < 300) v.z = src[2];
            }
            *(float4*)&tile[c][lw] = v;
        }
        __syncthreads();
        const int sc = (threadIdx.x & 7) * 8;     // 8 channels -> 16B store
        const int sw0 = threadIdx.x >> 3;         // 0..31
#pragma unroll
        for (int i = 0; i < 2; ++i) {
            const int wl = sw0 + i * 32;
            const int w = w0 + wl;
            if (w < 300) {
                __hip_bfloat16 p[8];
#pragma unroll
                for (int j = 0; j < 8; ++j) p[j] = __float2bfloat16(tile[sc + j][wl]);
                *(uint4*)&X3[(((size_t)(b * 16 + h) * 300 + w)) * 512 + c0 + sc] = *(uint4*)p;
            }
        }
    } else {
        // ---- pack_a ----
        float* w = smem;
        const int co = f - 10240;                 // 0..639
        if (co < 522) {
            const float4* src = (co < 512) ? (const float4*)(conv_w + (size_t)co * 3584)
                                           : (const float4*)(cc_w + (size_t)(co - 512) * 3584);
            for (int i = threadIdx.x; i < 896; i += 256) *(float4*)&w[i * 4] = src[i];
        } else {
            for (int i = threadIdx.x; i < 3584; i += 256) w[i] = 0.f;
        }
        __syncthreads();
        const int g = co >> 4, fl = co & 15;
        for (int chunk = threadIdx.x; chunk < 448; chunk += 256) {
            const int kk0 = chunk * 8;
            const int kt = kk0 >> 5, sq = (kk0 >> 3) & 3;
            __hip_bfloat16 p[8];
#pragma unroll
            for (int j = 0; j < 8; ++j) {
                const int k = kk0 + j;
                p[j] = __float2bfloat16(w[(k & 511) * 7 + (k >> 9)]);
            }
            char* dst = (char*)A2f + (((size_t)g * 112 + kt) * 64 + sq * 16 + fl) * 16;
            *(uint4*)dst = *(uint4*)p;
        }
    }
}

// ---------------------------------------------------------------------------
// scores_gemm: 10 cc rows, M=16 MFMA, barrier-free + LDS-free staging.
// Each lane loads A-/B-fragments straight from global (X3 is L3-resident);
// fused softmax/assign/asum epilogue; also zeroes agg.
// grid 768 = 8 XCD * (2 b * 48 nt of 64 n); block 256 (4 waves * 16 n).
// ---------------------------------------------------------------------------
__global__ __launch_bounds__(256) void scores_gemm(
    const __hip_bfloat16* __restrict__ A2f, const __hip_bfloat16* __restrict__ X3,
    const float* __restrict__ cc_b, float* __restrict__ assign,
    float* __restrict__ asum_part, float* __restrict__ agg) {
    __shared__ float sred[4][4][4];            // [wave][sq][r] asum partials
    const int tid = threadIdx.x;
    const int wv = tid >> 6;
    const int lane = tid & 63;
    const int fl = lane & 15;
    const int sq = lane >> 4;
    const int gid = blockIdx.x;
    const int xcd = gid & 7;
    const int j = gid >> 3;                    // 0..95
    const int b = xcd * 2 + (j >= 48 ? 1 : 0);
    const int nt = j % 48;                     // 64-wide n tile

    // ---- agg zero (81920 floats over 768 blocks) ----
    {
        const int base = gid * 107;
        for (int i = tid; i < 107; i += 256) {
            const int idx = base + i;
            if (idx < 81920) agg[idx] = 0.f;
        }
    }

    // this lane's output column n; B-frag source row (clamped for pad lanes)
    const int n = nt * 64 + wv * 16 + fl;
    const int nc = n > 2999 ? 2999 : n;
    const char* gB = (const char*)X3 + ((size_t)(b * 4800 + nc)) * 1024 + sq * 16;
    const char* Af = (const char*)A2f + (((size_t)32 * 112) << 10) + ((size_t)lane << 4);

    f32x4 acc = {};
#pragma unroll 4
    for (int kt = 0; kt < 112; ++kt) {
        const bf16x8 a  = *(const bf16x8*)(Af + ((size_t)kt << 10));
        const bf16x8 bv = *(const bf16x8*)(gB + (size_t)(kt >> 4) * 307200 + (size_t)(kt & 15) * 64);
        acc = __builtin_amdgcn_mfma_f32_16x16x32_bf16(a, bv, acc, 0, 0, 0);
    }

    // ---- fused softmax over k + assign write + asum partials ----
    float s[4];
#pragma unroll
    for (int r = 0; r < 4; ++r) {
        const int k = sq * 4 + r;
        s[r] = (k < 10) ? (acc[r] + cc_b[k]) : -1e30f;
    }
    float mx = fmaxf(fmaxf(s[0], s[1]), fmaxf(s[2], s[3]));
    mx = fmaxf(mx, __shfl_xor(mx, 16, 64));
    mx = fmaxf(mx, __shfl_xor(mx, 32, 64));
    float e[4], es = 0.f;
#pragma unroll
    for (int r = 0; r < 4; ++r) {
        e[r] = (sq * 4 + r < 10) ? __expf(s[r] - mx) : 0.f;
        es += e[r];
    }
    es += __shfl_xor(es, 16, 64);
    es += __shfl_xor(es, 32, 64);
    const float inv = 1.f / es;
    const bool nval = (n < 3000);
    float pa[4];
#pragma unroll
    for (int r = 0; r < 4; ++r) {
        const int k = sq * 4 + r;
        const float a = e[r] * inv;
        pa[r] = nval ? a : 0.f;
        if (nval && k < 10) assign[(size_t)(b * 10 + k) * 3000 + n] = a;
    }
#pragma unroll
    for (int off = 1; off < 16; off <<= 1)
#pragma unroll
        for (int r = 0; r < 4; ++r) pa[r] += __shfl_xor(pa[r], off, 64);
    if (fl == 0) {
#pragma unroll
        for (int r = 0; r < 4; ++r) sred[wv][sq][r] = pa[r];
    }
    __syncthreads();
    if (tid < 10)
        asum_part[(nt * 16 + b) * 10 + tid] =
            sred[0][tid >> 2][tid & 3] + sred[1][tid >> 2][tid & 3] +
            sred[2][tid >> 2][tid & 3] + sred[3][tid >> 2][tid & 3];
}

// ---------------------------------------------------------------------------
// conv_gemm: implicit-im2col MFMA GEMM (m 0..511) with FUSED aggregation.
// Epilogue: transpose-reduce (15 shfl/k, bit-identical pairing tree; lane fl
// owns slot bitrev4(fl)), cross-wave LDS combine halves global atomics.
//  - __launch_bounds__(256,4): 128-reg budget. Do NOT raise the min-waves
//    bound (a previous (256,6) forced acc spill -> 7.5 GB scratch).
// grid 1536 = 8 XCD * 48 (b,nt) * 4 m.  [FROZEN this round]
// ---------------------------------------------------------------------------
__global__ __launch_bounds__(256, 4) void conv_gemm(
    const __hip_bfloat16* __restrict__ A2f, const __hip_bfloat16* __restrict__ X3,
    const float* __restrict__ conv_b, const float* __restrict__ assign,
    float* __restrict__ agg) {
    __shared__ __align__(16) char lds[16384];   // B only: ph0 [0,8K) ph1 [8K,16K)
    const int tid = threadIdx.x;
    const int wv = tid >> 6;
    const int lane = tid & 63;

    // XCD-aware remap
    const int gid = blockIdx.x;
    const int xcd = gid & 7;
    const int j = gid >> 3;                    // 0..191
    const int nb = xcd * 48 + (j >> 2);        // 0..383
    const int m0 = (j & 3) * 128;              // 0,128,256,384
    const int b = nb / 24;
    const int nt = nb % 24;

    // ---- B staging (global -> LDS) ----
    const int row0 = wv * 16 + (lane >> 2);            // 0..63
    const int kseg = (lane & 3) ^ ((lane >> 3) & 3);   // XOR-swizzled source segment
    int n0 = nt * 128 + row0;      if (n0 > 2999) n0 = 2999;
    int n1 = nt * 128 + row0 + 64; if (n1 > 2999) n1 = 2999;
    const char* gB0 = (const char*)X3 + ((size_t)((b * 16 + n0 / 300) * 300 + n0 % 300)) * 1024 + (size_t)kseg * 16;
    const char* gB1 = (const char*)X3 + ((size_t)((b * 16 + n1 / 300) * 300 + n1 % 300)) * 1024 + (size_t)kseg * 16;
    char* lB = lds + wv * 1024 + lane * 16;            // +4096: rows 64..127

    // ---- fragment read offsets ----
    const int wm = (wv & 1) * 64;
    const int wn = (wv >> 1) * 64;
    const int fl = lane & 15;
    const int sq = lane >> 4;
    int boff[4];
#pragma unroll
    for (int i = 0; i < 4; ++i) {
        const int swz = (sq ^ ((fl >> 1) & 3)) * 16;
        boff[i] = (wn + i * 16 + fl) * 64 + swz;
    }
    // A fragment source (fragment-order A2f, coalesced)
    const char* Af = (const char*)A2f;
    const int gb = (m0 >> 4) + ((wv & 1) << 2);        // row-group base for this wave

    f32x4 acc[4][4] = {};
    bf16x8 aC[4], aN[4];

#define ISSUE_B(kt, ph)                                                                \
    {                                                                                  \
        const size_t badd = (size_t)((kt) >> 4) * 307200 + (size_t)((kt) & 15) * 64;   \
        async16(gB0 + badd, lB + (ph) * 8192);                                         \
        async16(gB1 + badd, lB + (ph) * 8192 + 4096);                                  \
    }
#define PRE_A(kt, arr)                                                                 \
    {                                                                                  \
        _Pragma("unroll")                                                              \
        for (int mi = 0; mi < 4; ++mi)                                                 \
            arr[mi] = *(const bf16x8*)(Af + (((size_t)(gb + mi) * 112 + (kt)) << 10) + (lane << 4)); \
    }
#define COMPUTE(ph, arr)                                                               \
    {                                                                                  \
        _Pragma("unroll")                                                              \
        for (int ni = 0; ni < 4; ++ni) {                                               \
            const bf16x8 bv = *(const bf16x8*)(lds + (ph) * 8192 + boff[ni]);          \
            _Pragma("unroll")                                                          \
            for (int mi = 0; mi < 4; ++mi)                                             \
                acc[mi][ni] = __builtin_amdgcn_mfma_f32_16x16x32_bf16(arr[mi], bv, acc[mi][ni], 0, 0, 0); \
        }                                                                              \
    }

    ISSUE_B(0, 0);
    PRE_A(0, aC);
    for (int kt = 0; kt < 112; kt += 2) {
        __syncthreads();                       // vmcnt(0) drain: B(kt) + aC landed
        ISSUE_B(kt + 1, 1);
        PRE_A(kt + 1, aN);
        COMPUTE(0, aC);
        __syncthreads();                       // B(kt+1) + aN landed; buf0 reads done
        if (kt < 110) { ISSUE_B(kt + 2, 0); PRE_A(kt + 2, aC); }
        COMPUTE(1, aN);
    }
#undef ISSUE_B
#undef PRE_A
#undef COMPUTE

    // ---- epilogue: bias+relu in-register, then fused agg ----
    const int quad4 = sq * 4;
#pragma unroll
    for (int mi = 0; mi < 4; ++mi) {
        const int cob = m0 + wm + mi * 16 + quad4;
        const float b0 = conv_b[cob + 0], b1 = conv_b[cob + 1],
                    b2 = conv_b[cob + 2], b3 = conv_b[cob + 3];
#pragma unroll
        for (int ni = 0; ni < 4; ++ni) {
            acc[mi][ni][0] = fmaxf(acc[mi][ni][0] + b0, 0.f);
            acc[mi][ni][1] = fmaxf(acc[mi][ni][1] + b1, 0.f);
            acc[mi][ni][2] = fmaxf(acc[mi][ni][2] + b2, 0.f);
            acc[mi][ni][3] = fmaxf(acc[mi][ni][3] + b3, 0.f);
        }
    }
    int nn[4];
#pragma unroll
    for (int ni = 0; ni < 4; ++ni) nn[ni] = nt * 128 + wn + ni * 16 + fl;
    const float* asg = assign + (size_t)b * 30000;
    // lane will own slot s = bitrev4(fl) after the transpose-reduce
    const int s_ = ((fl & 1) << 3) | ((fl & 2) << 1) | ((fl & 4) >> 1) | ((fl & 8) >> 3);
    const int co_off = (s_ >> 2) * 16 + quad4 + (s_ & 3);    // 0..63 within wm half
    float red10[10];
    for (int k = 0; k < 10; ++k) {
        float av[4];
#pragma unroll
        for (int ni = 0; ni < 4; ++ni)
            av[ni] = (nn[ni] < 3000) ? asg[(size_t)k * 3000 + nn[ni]] : 0.f;
        float part[16];
#pragma unroll
        for (int mi = 0; mi < 4; ++mi)
#pragma unroll
            for (int r = 0; r < 4; ++r)
                part[mi * 4 + r] = av[0] * acc[mi][0][r] + av[1] * acc[mi][1][r]
                                 + av[2] * acc[mi][2][r] + av[3] * acc[mi][3][r];
        // butterfly transpose-reduce over the 16 fl lanes: 8+4+2+1 = 15 shfl
#pragma unroll
        for (int bit = 0; bit < 4; ++bit) {
            const int off = 1 << bit;
            const int h = 8 >> bit;
            const bool hi = (fl >> bit) & 1;
#pragma unroll
            for (int jj = 0; jj < h; ++jj) {
                const float mine = hi ? part[jj + h] : part[jj];
                const float send = hi ? part[jj] : part[jj + h];
                part[jj] = mine + __shfl_xor(send, off, 64);
            }
        }
        red10[k] = part[0];
    }
    // cross-wave combine: waves 0,1 (wn=0) park in dead ph0 LDS; waves 2,3 add
    float* sagg = (float*)lds;                 // [2 wm-half][10 k][64 co_off]
    if (wv < 2) {
#pragma unroll
        for (int k = 0; k < 10; ++k) sagg[((wv * 10 + k) << 6) + co_off] = red10[k];
    }
    __syncthreads();
    if (wv >= 2) {
        const int wmh = wv & 1;
#pragma unroll
        for (int k = 0; k < 10; ++k) {
            const float v = red10[k] + sagg[((wmh * 10 + k) << 6) + co_off];
            atomicAdd(&agg[(size_t)(b * 10 + k) * 512 + m0 + wm + co_off], v);
        }
    }
}

// ---------------------------------------------------------------------------
// fc_fused: residual + L2-normalize (k<8) + fc + relu -> out[0:8192].
// v2: block 1024 (16 waves/CU, was 4) -- the old 256-thread/1-block/CU shape
// was 1 wave/SIMD, pure latency chain. grid (16 co-tiles, 16 b).
// Residual phase: k = (t>>9) + 2*jj is compile-time-static per jj (t>>9 is
// wave-uniform). fc phase: 32 k-split lanes per co, width-32 shfl tree.
// ---------------------------------------------------------------------------
__global__ __launch_bounds__(1024) void fc_fused(const float* __restrict__ agg,
                                                 const float* __restrict__ asum_part,
                                                 const float* __restrict__ centroids,
                                                 const float* __restrict__ fc_w,
                                                 const float* __restrict__ fc_b,
                                                 float* __restrict__ out) {
    __shared__ float res[4096];
    __shared__ float sasum[8];
    __shared__ float red2[16][4];
    __shared__ float scale[8];
    const int b = blockIdx.y;
    const int t = threadIdx.x;
    if (t < 8) {
        float s = 0.f;
#pragma unroll
        for (int p = 0; p < 48; ++p) s += asum_part[(p * 16 + b) * 10 + t];
        sasum[t] = s;
    }
    __syncthreads();
    const int b0 = t >> 9;                     // wave-uniform (0 or 1)
    float sqv[4] = {0.f, 0.f, 0.f, 0.f};
#pragma unroll
    for (int jj = 0; jj < 4; ++jj) {
        const int i = t + jj * 1024;
        const int k = b0 + jj * 2;
        const int c = i & 511;
        const float r = agg[(size_t)(b * 10 + k) * 512 + c] - sasum[k] * centroids[k * 512 + c];
        res[i] = r;
        sqv[jj] += r * r;
    }
    const int lane = t & 63, w = t >> 6;
#pragma unroll
    for (int jj = 0; jj < 4; ++jj) {
        float v = sqv[jj];
        for (int off = 32; off; off >>= 1) v += __shfl_xor(v, off, 64);
        if (lane == 0) red2[w][jj] = v;        // wave w holds k = (w>>3) + 2*jj
    }
    __syncthreads();
    if (t < 8) {
        const int half = (t & 1) * 8;          // waves with matching b0 = k&1
        const int jj = t >> 1;                 // k = (k&1) + 2*(k>>1)
        float ss = 0.f;
#pragma unroll
        for (int i2 = 0; i2 < 8; ++i2) ss += red2[half + i2][jj];
        scale[t] = 1.f / fmaxf(sqrtf(ss), 1e-12f);
    }
    __syncthreads();

    const int col = t >> 5;                    // 32 cols per block
    const int ks = t & 31;                     // 32 k-split lanes per col
    const int co = blockIdx.x * 32 + col;
    const float4* w4 = (const float4*)(fc_w + (size_t)co * 4096);
    float acc = 0.f;
#pragma unroll 4
    for (int j2 = 0; j2 < 32; ++j2) {
        const int i = ks + 32 * j2;            // k-index = j2>>2 (no carry past 128)
        const float4 wv = w4[i];
        const float4 rv = *(const float4*)&res[i * 4];
        acc += (rv.x * wv.x + rv.y * wv.y + rv.z * wv.z + rv.w * wv.w) * scale[j2 >> 2];
    }
    acc += __shfl_down(acc, 16, 32);
    acc += __shfl_down(acc, 8, 32);
    acc += __shfl_down(acc, 4, 32);
    acc += __shfl_down(acc, 2, 32);
    acc += __shfl_down(acc, 1, 32);
    if (ks == 0) out[b * 512 + co] = fmaxf(acc + fc_b[co], 0.f);
}

// ---------------------------------------------------------------------------
// logit: XCD-grouped, block 1024 (was 256): 4 k-split lanes per output,
// width-4 shfl reduce. grid 384 (24 otile * 16 b).
// ---------------------------------------------------------------------------
__global__ __launch_bounds__(1024) void logit_kernel(const float* __restrict__ emb,
                                                     const float* __restrict__ logit_w,
                                                     float* __restrict__ out) {
    __shared__ float se[512];
    const int gid = blockIdx.x;
    const int xcd = gid & 7;
    const int j = gid >> 3;
    const int otile = xcd * 3 + (j >> 4);
    const int b = j & 15;
    if (threadIdx.x < 512) se[threadIdx.x] = emb[b * 512 + threadIdx.x];
    __syncthreads();
    const int ol = threadIdx.x >> 2;           // 0..255
    const int ks = threadIdx.x & 3;
    const int o = otile * 256 + ol;
    if (o < 5994) {
        const float4* w4 = (const float4*)(logit_w + (size_t)o * 512);
        float acc = 0.f;
#pragma unroll 8
        for (int j2 = 0; j2 < 32; ++j2) {
            const int i = ks + 4 * j2;
            const float4 w = w4[i];
            acc += w.x * se[4 * i] + w.y * se[4 * i + 1] + w.z * se[4 * i + 2] + w.w * se[4 * i + 3];
        }
        acc += __shfl_down(acc, 2, 4);
        acc += __shfl_down(acc, 1, 4);
        if (ks == 0) out[8192 + b * 5994 + o] = acc;
    }
}

extern "C" void kernel_launch(void* const* d_in, const int* in_sizes, int n_in,
                              void* d_out, int out_size, void* d_ws, size_t ws_size,
                              hipStream_t stream) {
    (void)in_sizes; (void)n_in; (void)out_size; (void)ws_size;
    const float* x5       = (const float*)d_in[0];
    const float* conv_w   = (const float*)d_in[5];
    const float* conv_b   = (const float*)d_in[6];
    const float* cc_w     = (const float*)d_in[7];
    const float* cc_b     = (const float*)d_in[8];
    const float* centroids= (const float*)d_in[9];
    const float* fc_w     = (const float*)d_in[10];
    const float* fc_b     = (const float*)d_in[11];
    const float* logit_w  = (const float*)d_in[12];
    float* out = (float*)d_out;

    char* ws = (char*)d_ws;
    __hip_bfloat16* X3  = (__hip_bfloat16*)(ws);              // 78,643,200 B
    __hip_bfloat16* A2f = (__hip_bfloat16*)(ws + 78643200);   //  4,587,520 B (fragment-order)
    float* assign       = (float*)(ws + 83230720);            //  1,920,000 B
    float* asum_part    = (float*)(ws + 85150720);            //     30,720 B (48 partials)
    float* agg          = (float*)(ws + 85181440);            //    327,680 B

    pack_all<<<dim3(10880), 256, 0, stream>>>(x5, conv_w, cc_w, X3, A2f);
    scores_gemm<<<dim3(768), 256, 0, stream>>>(A2f, X3, cc_b, assign, asum_part, agg);
    conv_gemm<<<dim3(1536), 256, 0, stream>>>(A2f, X3, conv_b, assign, agg);
    fc_fused<<<dim3(16, 16), 1024, 0, stream>>>(agg, asum_part, centroids, fc_w, fc_b, out);
    logit_kernel<<<dim3(384), 1024, 0, stream>>>(out, logit_w, out);
}